// Round 3
// baseline (297.854 us; speedup 1.0000x reference)
//
#include <hip/hip_runtime.h>
#include <hip/hip_bf16.h>

// Beamform v3: LDS-staged, all global accesses lane-contiguous.
// Each workgroup (256 threads) processes 256 beamform-blocks (40 KB input,
// 10 KB output) from one channel:
//   Phase 1: coalesced float4 loads (lane i -> base + i*16B) -> b128 LDS writes.
//   Phase 2: per-(block,col) gather from LDS (b64, ~4-way conflicts), complex
//            combine, scalar writes to LDS out-staging.
//   Phase 3: coalesced float2 stores from LDS out-staging to global.

#define BLOCKS_PER_WG 256   // beamform blocks (20 complex samples each) per WG
#define WG 256              // threads per workgroup

__global__ __launch_bounds__(WG) void beamform_kernel(
    const float* __restrict__ in0, const float* __restrict__ in1,
    const float* __restrict__ in2, const float* __restrict__ in3,
    const float* __restrict__ bf, float* __restrict__ out,
    int blocksPerChannel)
{
    __shared__ __align__(16) float lds_in[BLOCKS_PER_WG * 40];   // 40 KB
    __shared__ __align__(16) float lds_out[BLOCKS_PER_WG * 10];  // 10 KB

    const int t = threadIdx.x;
    const int g = blockIdx.x;        // wg index within channel
    const int ch = blockIdx.y;       // channel 0..3

    const float* __restrict__ in =
        (ch == 0) ? in0 : (ch == 1) ? in1 : (ch == 2) ? in2 : in3;

    const int blockStart = g * BLOCKS_PER_WG;
    const int nblk = min(BLOCKS_PER_WG, blocksPerChannel - blockStart);

    // Uniform beamforming weights (L1-cached).
    const float br0 = bf[0], bi0 = bf[1];
    const float br1 = bf[2], bi1 = bf[3];
    const float br2 = bf[4], bi2 = bf[5];
    const float br3 = bf[6], bi3 = bf[7];

    // ---- Phase 1: global -> LDS, perfectly coalesced float4 ----
    const float4* __restrict__ gin =
        reinterpret_cast<const float4*>(in + (size_t)blockStart * 40);

    if (nblk == BLOCKS_PER_WG) {
#pragma unroll
        for (int k = 0; k < 10; ++k) {
            const int f = k * WG + t;                 // float4 index, 0..2559
            float4 v = gin[f];
            *reinterpret_cast<float4*>(&lds_in[4 * f]) = v;   // ds_write_b128
        }
    } else {
        const int nf4 = nblk * 10;
#pragma unroll
        for (int k = 0; k < 10; ++k) {
            const int f = k * WG + t;
            if (f < nf4) {
                float4 v = gin[f];
                *reinterpret_cast<float4*>(&lds_in[4 * f]) = v;
            }
        }
    }
    __syncthreads();

    // ---- Phase 2: gather + complex combine, results into lds_out ----
    // Task tt = (bl, c): bl = tt/5, c = tt%5. Reads float2 at words
    // 40*bl + 10*r + 2*c (r=0..3), writes lds_out[10*bl + c] and [10*bl+5+c].
#pragma unroll
    for (int k = 0; k < 5; ++k) {
        const int tt = k * WG + t;                    // 0..1279
        if (tt < nblk * 5) {
            const int bl = tt / 5;
            const int c  = tt - bl * 5;
            const float* __restrict__ x = &lds_in[40 * bl + 2 * c];
            const float2 x0 = *reinterpret_cast<const float2*>(&x[0]);
            const float2 x1 = *reinterpret_cast<const float2*>(&x[10]);
            const float2 x2 = *reinterpret_cast<const float2*>(&x[20]);
            const float2 x3 = *reinterpret_cast<const float2*>(&x[30]);

            float re = br0 * x0.x - bi0 * x0.y;
            float im = bi0 * x0.x + br0 * x0.y;
            re += br1 * x1.x - bi1 * x1.y;
            im += bi1 * x1.x + br1 * x1.y;
            re += br2 * x2.x - bi2 * x2.y;
            im += bi2 * x2.x + br2 * x2.y;
            re += br3 * x3.x - bi3 * x3.y;
            im += bi3 * x3.x + br3 * x3.y;

            lds_out[10 * bl + c]     = re;
            lds_out[10 * bl + 5 + c] = im;
        }
    }
    __syncthreads();

    // ---- Phase 3: LDS -> global, perfectly coalesced float2 ----
    const float2* __restrict__ lo = reinterpret_cast<const float2*>(lds_out);
    float2* __restrict__ gout = reinterpret_cast<float2*>(
        out + ((size_t)ch * blocksPerChannel + blockStart) * 10);
    const int nf2 = nblk * 5;
#pragma unroll
    for (int k = 0; k < 5; ++k) {
        const int j = k * WG + t;                     // float2 index, 0..1279
        if (j < nf2) {
            gout[j] = lo[j];
        }
    }
}

extern "C" void kernel_launch(void* const* d_in, const int* in_sizes, int n_in,
                              void* d_out, int out_size, void* d_ws, size_t ws_size,
                              hipStream_t stream)
{
    const float* in0 = (const float*)d_in[0];
    const float* in1 = (const float*)d_in[1];
    const float* in2 = (const float*)d_in[2];
    const float* in3 = (const float*)d_in[3];
    const float* bf  = (const float*)d_in[4];
    float* out = (float*)d_out;

    const int len = in_sizes[0];               // 20,000,000 interleaved floats
    const int blocksPerChannel = len / 40;     // 500,000 blocks / channel

    dim3 grid((blocksPerChannel + BLOCKS_PER_WG - 1) / BLOCKS_PER_WG, 4, 1);
    beamform_kernel<<<grid, dim3(WG, 1, 1), 0, stream>>>(
        in0, in1, in2, in3, bf, out, blocksPerChannel);
}